// Round 12
// baseline (284.789 us; speedup 1.0000x reference)
//
#include <hip/hip_runtime.h>
#include <cmath>

#define NN 50000
#define NE 800000
#define PAD 96   // per-dst slot cap; P(Poisson(16) > 96) ~ 1e-40
// int32-overflow boundary of the reference's argsort key (jax x64 disabled):
// key = dst*50000+src wraps for dst>42949, or dst==42949 && src>=33648.
// VERIFIED round 3: jax order = rotate(bucket, s0), norm indexed by UNROTATED j
// (rnrm at sorted position idx pairs with j = idx - s0 mod NE, src = RAW src array).
#define DST_HI 42949
#define SRC_CUT 33648

// ---- kA: aux FIRST (lesson R9), then rank-only atomic pass (coalesced rank store) ----
// [0,196): rptr + dout   [196,276): Weff   [276,3401): rank
__global__ __launch_bounds__(256) void k_A(const int* __restrict__ src, const int* __restrict__ dst,
                                           const float* __restrict__ ew,
                                           int* __restrict__ cnt, int* __restrict__ rank,
                                           int* __restrict__ rptr, float* __restrict__ dout,
                                           const float* __restrict__ Wz, const float* __restrict__ Wh,
                                           float* __restrict__ Weff) {
  int bid = blockIdx.x;
  if (bid >= 276) {
    int e = (bid - 276) * 256 + threadIdx.x;
    if (e < NE) rank[e] = atomicAdd(&cnt[dst[e]], 1);
  } else if (bid < 196) {
    int i = bid * 256 + threadIdx.x;
    if (i >= NN) return;
    int lo = 0, hi = NE;
    while (lo < hi) { int m = (lo + hi) >> 1; if (src[m] < i) lo = m + 1; else hi = m; }
    int lo2 = lo, hi2 = NE;
    while (lo2 < hi2) { int m = (lo2 + hi2) >> 1; if (src[m] < i + 1) lo2 = m + 1; else hi2 = m; }
    rptr[i] = lo;
    if (i == NN - 1) rptr[NN] = lo2;
    float a = 0.f;
    for (int p = lo; p < lo2; ++p) a += ew[p];
    dout[i] = a;
  } else {
    int idx = (bid - 196) * 256 + threadIdx.x;  // 80*256 == 160*128 exactly
    int kk = idx >> 7, f = idx & 127;
    int blk = kk >> 5, c = kk & 31;
    const float* W = (f < 64) ? Wz : Wh;
    int fl = f & 63;
    float v;
    if (blk == 0)      v = W[c * 64 + fl] + W[18432 + c * 64 + fl];
    else if (blk == 1) v = W[6144 + c * 64 + fl];
    else if (blk == 2) v = W[18432 + 6144 + c * 64 + fl];
    else if (blk == 3) v = W[2 * 6144 + c * 64 + fl];
    else               v = W[18432 + 2 * 6144 + c * 64 + fl];
    Weff[idx] = v;
  }
}

// ---- kB: scan1 (blocks [0,49)) ∥ atomic-free packed pad-scatter (blocks [49,831)) ----
// pad4 entry {e, src[e], ew[e], 0}: 16B scatter dirties the same 64B line as 4B (lesson R10).
__global__ __launch_bounds__(1024) void k_B(const int* __restrict__ cnt, int* __restrict__ outp,
                                            int* __restrict__ partials,
                                            const int* __restrict__ src, const int* __restrict__ dst,
                                            const float* __restrict__ ew, const int* __restrict__ rank,
                                            int4* __restrict__ pad4) {
  if (blockIdx.x >= 49) {
    int e = (blockIdx.x - 49) * 1024 + threadIdx.x;
    if (e < NE) {
      int r = rank[e];
      if (r < PAD) pad4[dst[e] * PAD + r] = make_int4(e, src[e], __float_as_int(ew[e]), 0);
    }
    return;
  }
  __shared__ int tmp[1024];
  int i = blockIdx.x * 1024 + threadIdx.x;
  int v = (i < NN) ? cnt[i] : 0;
  tmp[threadIdx.x] = v;
  __syncthreads();
  for (int off = 1; off < 1024; off <<= 1) {
    int t = (threadIdx.x >= (unsigned)off) ? tmp[threadIdx.x - off] : 0;
    __syncthreads();
    tmp[threadIdx.x] += t;
    __syncthreads();
  }
  if (i < NN) outp[i] = tmp[threadIdx.x] - v;  // exclusive within segment
  if (threadIdx.x == 1023) partials[blockIdx.x] = tmp[1023];
}

// ---- kC: scan3 (blocks [0,196)) ∥ din from packed pad (blocks [196,1759), 8 lanes/node) ----
// din must complete BEFORE sortw: cnr reads din of arbitrary nodes (race lesson R10).
__global__ __launch_bounds__(256) void k_C(int* __restrict__ outp, const int* __restrict__ partials,
                                           const int* __restrict__ cnt, const int4* __restrict__ pad4,
                                           float* __restrict__ din) {
  if (blockIdx.x >= 196) {
    int g = (blockIdx.x - 196) * 256 + threadIdx.x;
    int node = g >> 3, lane = g & 7;
    if (node >= NN) return;
    int n = cnt[node]; if (n > PAD) n = PAD;
    float a = 0.f;
    for (int i = lane; i < n; i += 8) a += __int_as_float(pad4[node * PAD + i].z);
    a += __shfl_down(a, 4, 8);
    a += __shfl_down(a, 2, 8);
    a += __shfl_down(a, 1, 8);
    if (lane == 0) din[node] = a;
    return;
  }
  __shared__ int sbase;
  int seg = (blockIdx.x * 256) >> 10;
  if (threadIdx.x == 0) {
    int s = 0;
    for (int k = 0; k < seg; ++k) s += partials[k];
    sbase = s;
  }
  __syncthreads();
  int i = blockIdx.x * 256 + threadIdx.x;
  if (i < NN) outp[i] += sbase;
  else if (i == NN) outp[i] = NE;
}

// ---- s0: order-invariant count on the UNSORTED pad row of DST_HI ----
__global__ __launch_bounds__(128) void k_s0(const int* __restrict__ sp, const int4* __restrict__ pad4,
                                            const int* __restrict__ cnt, int* __restrict__ s0) {
  __shared__ int cs[2];
  int n = cnt[DST_HI]; if (n > PAD) n = PAD;
  int t = threadIdx.x;
  unsigned long long m = __ballot(t < n && pad4[DST_HI * PAD + t].y < SRC_CUT);
  if ((t & 63) == 0) cs[t >> 6] = (int)__popcll(m);
  __syncthreads();
  if (t == 0) *s0 = sp[DST_HI] + cs[0] + cs[1];
}

// ---- wave-per-dst: coalesced packed-pad read -> 64b-key bitonic sort -> cnf (coalesced)
//      + cnr (the ONE scatter; dst[v] == wv, src[j] read is coalesced) ----
__global__ __launch_bounds__(256) void k_sortw(const int* __restrict__ sp, const int4* __restrict__ pad4,
                                               const int* __restrict__ rawsrc,
                                               const float* __restrict__ dout, const float* __restrict__ din,
                                               const int* __restrict__ s0p,
                                               int2* __restrict__ cnf, int2* __restrict__ cnr) {
  int wv = (blockIdx.x * 256 + threadIdx.x) >> 6;
  int lane = threadIdx.x & 63;
  if (wv >= NN) return;
  int b0 = sp[wv], b1 = sp[wv + 1];
  int n = b1 - b0;
  int s0 = *s0p;
  if (n > 64) {  // 64<n<=96 safety path (never hit at Poisson(16))
    if (lane == 0) {
      int es[PAD], ss[PAD];
      int nn = n > PAD ? PAD : n;
      for (int i = 0; i < nn; ++i) { int4 pe = pad4[wv * PAD + i]; es[i] = pe.x; ss[i] = pe.y; }
      for (int i = 1; i < nn; ++i) {
        int ve = es[i], vs = ss[i]; int j = i - 1;
        while (j >= 0 && es[j] > ve) { es[j + 1] = es[j]; ss[j + 1] = ss[j]; --j; }
        es[j + 1] = ve; ss[j + 1] = vs;
      }
      for (int i = 0; i < nn; ++i) {
        int vs = ss[i];
        cnf[b0 + i] = make_int2(vs, __float_as_int(1.0f / dout[vs]));
        int j = b0 + i - s0; if (j < 0) j += NE;
        cnr[es[i]] = make_int2(wv, __float_as_int(1.0f / din[rawsrc[j]]));
      }
    }
    return;
  }
  unsigned long long k = ~0ULL;
  if (lane < n) {
    int4 pe = pad4[wv * PAD + lane];   // coalesced row read
    k = ((unsigned long long)(unsigned)pe.x << 32) | (unsigned)pe.y;  // key=e, payload=src
  }
  if (n > 1) {
#pragma unroll
    for (int kk = 2; kk <= 64; kk <<= 1) {
#pragma unroll
      for (int j = kk >> 1; j > 0; j >>= 1) {
        unsigned long long o = __shfl_xor(k, j, 64);
        bool lower = (lane & j) == 0;
        bool asc = (lane & kk) == 0;
        bool keepmin = (lower == asc);
        if (keepmin ? (o < k) : (o > k)) k = o;
      }
    }
  }
  if (lane < n) {
    int ve = (int)(k >> 32);
    int vs = (int)(k & 0xffffffffu);
    cnf[b0 + lane] = make_int2(vs, __float_as_int(1.0f / dout[vs]));   // coalesced
    int j = b0 + lane - s0; if (j < 0) j += NE;
    cnr[ve] = make_int2(wv, __float_as_int(1.0f / din[rawsrc[j]]));    // the one scatter
  }
}

// ---- fused pair of gather props: 8 lanes/row, float4/lane.
//      16-edge main loop: BOTH int2 chunk-loads issued up-front -> 16 gathers in flight. ----
__global__ __launch_bounds__(256) void k_prop2(const float* __restrict__ inA, const int* __restrict__ rpA,
                                               const int2* __restrict__ cnA, float* __restrict__ outA,
                                               const float* __restrict__ inB, const int* __restrict__ rpB,
                                               const int2* __restrict__ cnB, float* __restrict__ outB,
                                               const float* __restrict__ sub, float mul) {
  int t = blockIdx.x * 256 + threadIdx.x;
  const int half = NN * 8;
  const float* in; const int* rp; const int2* cn; float* out;
  if (t < half) { in = inA; rp = rpA; cn = cnA; out = outA; }
  else          { in = inB; rp = rpB; cn = cnB; out = outB; t -= half; }
  int r = t >> 3;
  if (r >= NN) return;
  int lane8 = t & 7;
  int c4 = lane8 * 4;
  int b = rp[r], e2 = rp[r + 1];
  float a0[4] = {0.f, 0.f, 0.f, 0.f}, a1[4] = {0.f, 0.f, 0.f, 0.f};
  int p = b;
  for (; p + 16 <= e2; p += 16) {
    int2 u = cn[p + lane8];              // both loads in flight before any gather
    int2 v = cn[p + 8 + lane8];
#pragma unroll
    for (int jj = 0; jj < 8; ++jj) {
      int col = __shfl(u.x, jj, 8);
      float w = __int_as_float(__shfl(u.y, jj, 8));
      const float4 xv = *(const float4*)&in[col * 32 + c4];
      float* a = (jj & 1) ? a1 : a0;
      a[0] += w * xv.x; a[1] += w * xv.y; a[2] += w * xv.z; a[3] += w * xv.w;
    }
#pragma unroll
    for (int jj = 0; jj < 8; ++jj) {
      int col = __shfl(v.x, jj, 8);
      float w = __int_as_float(__shfl(v.y, jj, 8));
      const float4 xv = *(const float4*)&in[col * 32 + c4];
      float* a = (jj & 1) ? a1 : a0;
      a[0] += w * xv.x; a[1] += w * xv.y; a[2] += w * xv.z; a[3] += w * xv.w;
    }
  }
  for (; p + 8 <= e2; p += 8) {
    int2 u = cn[p + lane8];
#pragma unroll
    for (int jj = 0; jj < 8; ++jj) {
      int col = __shfl(u.x, jj, 8);
      float w = __int_as_float(__shfl(u.y, jj, 8));
      const float4 xv = *(const float4*)&in[col * 32 + c4];
      float* a = (jj & 1) ? a1 : a0;
      a[0] += w * xv.x; a[1] += w * xv.y; a[2] += w * xv.z; a[3] += w * xv.w;
    }
  }
  for (; p < e2; ++p) {
    int2 c1 = cn[p];
    float w = __int_as_float(c1.y);
    const float4 xv = *(const float4*)&in[c1.x * 32 + c4];
    a0[0] += w * xv.x; a0[1] += w * xv.y; a0[2] += w * xv.z; a0[3] += w * xv.w;
  }
  float ax = a0[0] + a1[0], ay = a0[1] + a1[1], az = a0[2] + a1[2], aw = a0[3] + a1[3];
  float4 o;
  if (sub) {
    const float4 s = *(const float4*)&sub[r * 32 + c4];
    o.x = mul * ax - s.x; o.y = mul * ay - s.y; o.z = mul * az - s.z; o.w = mul * aw - s.w;
  } else {
    o.x = ax; o.y = ay; o.z = az; o.w = aw;
  }
  *(float4*)&out[r * 32 + c4] = o;
}

// ---- register-blocked GEMM + GRU epilogue: 64x128 tile, K-chunk 32 (25.6 KB LDS) ----
__global__ __launch_bounds__(256) void k_gemm(const float* __restrict__ X, const float* __restrict__ T1o,
                                              const float* __restrict__ T1i, const float* __restrict__ T2o,
                                              const float* __restrict__ T2i,
                                              const float* __restrict__ Weff,
                                              const float* __restrict__ bz, const float* __restrict__ bh,
                                              float* __restrict__ out) {
  __shared__ float Ws[32][128];
  __shared__ float Fs[64][36];
  const int tid = threadIdx.x;
  const int tx = tid & 15, ty = tid >> 4;
  const int rb = blockIdx.x * 64;
  float accz[4][4] = {{0.f}}, acch[4][4] = {{0.f}};

  for (int kc = 0; kc < 160; kc += 32) {
    __syncthreads();
#pragma unroll
    for (int i = 0; i < 4; ++i) {
      int q = tid + i * 256;
      int row = q >> 5, cv = q & 31;
      *(float4*)&Ws[row][cv * 4] = *(const float4*)&Weff[(kc + row) * 128 + cv * 4];
    }
    const int blk = kc >> 5;
    const float* base = (blk == 0) ? X : (blk == 1) ? T1o : (blk == 2) ? T1i : (blk == 3) ? T2o : T2i;
#pragma unroll
    for (int i = 0; i < 2; ++i) {
      int q = tid + i * 256;
      int row = q >> 3, kv = q & 7;
      int gr = rb + row;
      float4 v = make_float4(0.f, 0.f, 0.f, 0.f);
      if (gr < NN) v = *(const float4*)&base[gr * 32 + kv * 4];
      *(float4*)&Fs[row][kv * 4] = v;
    }
    __syncthreads();
#pragma unroll
    for (int k = 0; k < 32; ++k) {
      float fa[4];
#pragma unroll
      for (int ri = 0; ri < 4; ++ri) fa[ri] = Fs[ty * 4 + ri][k];
      float4 wz = *(float4*)&Ws[k][tx * 4];
      float4 wh = *(float4*)&Ws[k][64 + tx * 4];
#pragma unroll
      for (int ri = 0; ri < 4; ++ri) {
        accz[ri][0] += fa[ri] * wz.x; accz[ri][1] += fa[ri] * wz.y;
        accz[ri][2] += fa[ri] * wz.z; accz[ri][3] += fa[ri] * wz.w;
        acch[ri][0] += fa[ri] * wh.x; acch[ri][1] += fa[ri] * wh.y;
        acch[ri][2] += fa[ri] * wh.z; acch[ri][3] += fa[ri] * wh.w;
      }
    }
  }

  const float4 bzv = *(const float4*)&bz[tx * 4];
  const float4 bhv = *(const float4*)&bh[tx * 4];
#pragma unroll
  for (int ri = 0; ri < 4; ++ri) {
    int r = rb + ty * 4 + ri;
    if (r < NN) {
      float4 o;
      float z, h;
      z = 1.f / (1.f + expf(-(accz[ri][0] + bzv.x))); h = tanhf(acch[ri][0] + bhv.x); o.x = (1.f - z) * h;
      z = 1.f / (1.f + expf(-(accz[ri][1] + bzv.y))); h = tanhf(acch[ri][1] + bhv.y); o.y = (1.f - z) * h;
      z = 1.f / (1.f + expf(-(accz[ri][2] + bzv.z))); h = tanhf(acch[ri][2] + bhv.z); o.z = (1.f - z) * h;
      z = 1.f / (1.f + expf(-(accz[ri][3] + bzv.w))); h = tanhf(acch[ri][3] + bhv.w); o.w = (1.f - z) * h;
      *(float4*)&out[r * 64 + tx * 4] = o;
    }
  }
}

// ---------------- launch ----------------
extern "C" void kernel_launch(void* const* d_in, const int* in_sizes, int n_in,
                              void* d_out, int out_size, void* d_ws, size_t ws_size,
                              hipStream_t stream) {
  const float* X  = (const float*)d_in[0];
  const int*   ei = (const int*)d_in[1];
  const float* ew = (const float*)d_in[2];
  const float* Wz = (const float*)d_in[3];
  const float* bz = (const float*)d_in[4];
  const float* Wh = (const float*)d_in[7];
  const float* bh = (const float*)d_in[8];
  float* out = (float*)d_out;
  const int* src = ei;
  const int* dst = ei + NE;

  char* p = (char*)d_ws;
  auto alloc = [&](size_t bytes) -> char* {
    char* r = p;
    p += (bytes + 255) & ~(size_t)255;
    return r;
  };
  float* T1o     = (float*)alloc((size_t)NN * 32 * 4);
  float* T1i     = (float*)alloc((size_t)NN * 32 * 4);
  float* T2o     = (float*)alloc((size_t)NN * 32 * 4);
  float* T2i     = (float*)alloc((size_t)NN * 32 * 4);
  int4*  pad4    = (int4*)alloc((size_t)NN * PAD * 16);   // 76.8 MB packed, no memset needed
  int*   rank    = (int*)alloc((size_t)NE * 4);
  int2*  cnf     = (int2*)alloc((size_t)NE * 8);
  int2*  cnr     = (int2*)alloc((size_t)NE * 8);
  int*   sp      = (int*)alloc((NN + 1) * 4);
  int*   rptr    = (int*)alloc((NN + 1) * 4);
  int*   cnt     = (int*)alloc(NN * 4);
  int*   partial = (int*)alloc(64 * 4);
  float* dout    = (float*)alloc(NN * 4);
  float* din     = (float*)alloc(NN * 4);
  float* Weff    = (float*)alloc(160 * 128 * 4);
  int*   s0      = (int*)alloc(4);

  hipMemsetAsync(cnt, 0, NN * 4, stream);

  k_A<<<3401, 256, 0, stream>>>(src, dst, ew, cnt, rank, rptr, dout, Wz, Wh, Weff);
  k_B<<<831, 1024, 0, stream>>>(cnt, sp, partial, src, dst, ew, rank, pad4);   // scan1 ∥ scatter
  k_C<<<1759, 256, 0, stream>>>(sp, partial, cnt, pad4, din);                  // scan3 ∥ din
  k_s0<<<1, 128, 0, stream>>>(sp, pad4, cnt, s0);
  k_sortw<<<12500, 256, 0, stream>>>(sp, pad4, src, dout, din, s0, cnf, cnr);  // sort+cnf+cnr

  // T1o = Pf(X) (CSC gather), T1i = Pr(X) (CSR gather) — fused
  k_prop2<<<3125, 256, 0, stream>>>(X, sp, cnf, T1o,
                                    X, rptr, cnr, T1i, nullptr, 1.f);
  // T2 = 2*P(T1) - X (fused Chebyshev), pair fused
  k_prop2<<<3125, 256, 0, stream>>>(T1o, sp, cnf, T2o,
                                    T1i, rptr, cnr, T2i, X, 2.f);

  k_gemm<<<782, 256, 0, stream>>>(X, T1o, T1i, T2o, T2i, Weff, bz, bh, out);
}

// Round 14
// 277.347 us; speedup vs baseline: 1.0268x; 1.0268x over previous
//
#include <hip/hip_runtime.h>
#include <hip/hip_fp16.h>
#include <cmath>

#define NN 50000
#define NE 800000
#define PAD 96   // per-dst slot cap; P(Poisson(16) > 96) ~ 1e-40
// int32-overflow boundary of the reference's argsort key (jax x64 disabled):
// key = dst*50000+src wraps for dst>42949, or dst==42949 && src>=33648.
// VERIFIED round 3: jax order = rotate(bucket, s0), norm indexed by UNROTATED j
// (rnrm at sorted position idx pairs with j = idx - s0 mod NE, src = RAW src array).
#define DST_HI 42949
#define SRC_CUT 33648

__device__ __forceinline__ unsigned short f2h(float f) {  // RNE fp32 -> fp16 (11-bit mantissa)
  __half h = __float2half_rn(f);
  return *reinterpret_cast<unsigned short*>(&h);
}

// ---- kA (R11 fused structure, best measured): aux FIRST (lesson R9), rank+pad fused last.
// [0,196): rptr+dout   [196,276): Weff   [276,667): X->fp16   [667,3792): rank + packed pad scatter
// pad4 {e, src[e], ew[e], 0}: 16B scatter dirties the same 64B line as 4B (lesson R10).
__global__ __launch_bounds__(256) void k_A(const float* __restrict__ X, const int* __restrict__ src,
                                           const int* __restrict__ dst, const float* __restrict__ ew,
                                           int* __restrict__ cnt, int4* __restrict__ pad4,
                                           int* __restrict__ rptr, float* __restrict__ dout,
                                           const float* __restrict__ Wz, const float* __restrict__ Wh,
                                           float* __restrict__ Weff, unsigned short* __restrict__ Xh) {
  int bid = blockIdx.x;
  if (bid >= 667) {
    int e = (bid - 667) * 256 + threadIdx.x;
    if (e < NE) {
      int d = dst[e];
      int r = atomicAdd(&cnt[d], 1);
      if (r < PAD) pad4[d * PAD + r] = make_int4(e, src[e], __float_as_int(ew[e]), 0);
    }
  } else if (bid < 196) {
    int i = bid * 256 + threadIdx.x;
    if (i >= NN) return;
    int lo = 0, hi = NE;
    while (lo < hi) { int m = (lo + hi) >> 1; if (src[m] < i) lo = m + 1; else hi = m; }
    int lo2 = lo, hi2 = NE;
    while (lo2 < hi2) { int m = (lo2 + hi2) >> 1; if (src[m] < i + 1) lo2 = m + 1; else hi2 = m; }
    rptr[i] = lo;
    if (i == NN - 1) rptr[NN] = lo2;
    float a = 0.f;
    for (int p = lo; p < lo2; ++p) a += ew[p];
    dout[i] = a;
  } else if (bid < 276) {
    int idx = (bid - 196) * 256 + threadIdx.x;  // 80*256 == 160*128 exactly
    int kk = idx >> 7, f = idx & 127;
    int blk = kk >> 5, c = kk & 31;
    const float* W = (f < 64) ? Wz : Wh;
    int fl = f & 63;
    float v;
    if (blk == 0)      v = W[c * 64 + fl] + W[18432 + c * 64 + fl];
    else if (blk == 1) v = W[6144 + c * 64 + fl];
    else if (blk == 2) v = W[18432 + 6144 + c * 64 + fl];
    else if (blk == 3) v = W[2 * 6144 + c * 64 + fl];
    else               v = W[18432 + 2 * 6144 + c * 64 + fl];
    Weff[idx] = v;
  } else {
    // X -> fp16 copy: 1.6M elems, 16/thread
    int t = (bid - 276) * 256 + threadIdx.x;
    int base = t * 16;
    if (base >= NN * 32) return;
#pragma unroll
    for (int q = 0; q < 2; ++q) {
      const float4 a = *(const float4*)&X[base + q * 8];
      const float4 b = *(const float4*)&X[base + q * 8 + 4];
      ushort4 o1 = make_ushort4(f2h(a.x), f2h(a.y), f2h(a.z), f2h(a.w));
      ushort4 o2 = make_ushort4(f2h(b.x), f2h(b.y), f2h(b.z), f2h(b.w));
      *(ushort4*)&Xh[base + q * 8] = o1;
      *(ushort4*)&Xh[base + q * 8 + 4] = o2;
    }
  }
}

// ---- kB: scan1 (blocks [0,49)) ∥ din from packed pad (blocks [49,440), 8 lanes/node) ----
__global__ void k_B(const int* __restrict__ cnt, int* __restrict__ outp, int* __restrict__ partials,
                    const int4* __restrict__ pad4, float* __restrict__ din) {
  if (blockIdx.x >= 49) {
    int g = (blockIdx.x - 49) * 1024 + threadIdx.x;
    int node = g >> 3, lane = g & 7;
    if (node >= NN) return;
    int n = cnt[node]; if (n > PAD) n = PAD;
    float a = 0.f;
    for (int i = lane; i < n; i += 8) a += __int_as_float(pad4[node * PAD + i].z);
    a += __shfl_down(a, 4, 8);
    a += __shfl_down(a, 2, 8);
    a += __shfl_down(a, 1, 8);
    if (lane == 0) din[node] = a;
    return;
  }
  __shared__ int tmp[1024];
  int i = blockIdx.x * 1024 + threadIdx.x;
  int v = (i < NN) ? cnt[i] : 0;
  tmp[threadIdx.x] = v;
  __syncthreads();
  for (int off = 1; off < 1024; off <<= 1) {
    int t = (threadIdx.x >= (unsigned)off) ? tmp[threadIdx.x - off] : 0;
    __syncthreads();
    tmp[threadIdx.x] += t;
    __syncthreads();
  }
  if (i < NN) outp[i] = tmp[threadIdx.x] - v;  // exclusive within segment
  if (threadIdx.x == 1023) partials[blockIdx.x] = tmp[1023];
}

// ---- kC: scan3 (each block redundantly prefix-sums its partials) ----
__global__ __launch_bounds__(256) void k_C(int* __restrict__ outp, const int* __restrict__ partials) {
  __shared__ int sbase;
  int seg = (blockIdx.x * 256) >> 10;
  if (threadIdx.x == 0) {
    int s = 0;
    for (int k = 0; k < seg; ++k) s += partials[k];
    sbase = s;
  }
  __syncthreads();
  int i = blockIdx.x * 256 + threadIdx.x;
  if (i < NN) outp[i] += sbase;
  else if (i == NN) outp[i] = NE;
}

// ---- wave-per-dst: coalesced pad read -> 64b-key bitonic sort -> cnf (coalesced)
//      + cnr (the ONE scatter).  s0 computed inline per block. ----
__global__ __launch_bounds__(256) void k_sortw(const int* __restrict__ sp, const int4* __restrict__ pad4,
                                               const int* __restrict__ rawsrc, const int* __restrict__ cnt,
                                               const float* __restrict__ dout, const float* __restrict__ din,
                                               int2* __restrict__ cnf, int2* __restrict__ cnr) {
  __shared__ int s0s;
  {
    int t = threadIdx.x;
    if (t < 64) {
      int nh = cnt[DST_HI]; if (nh > PAD) nh = PAD;
      int c = 0;
      for (int i = t; i < nh; i += 64) c += (pad4[DST_HI * PAD + i].y < SRC_CUT);
      c += __shfl_xor(c, 32, 64); c += __shfl_xor(c, 16, 64); c += __shfl_xor(c, 8, 64);
      c += __shfl_xor(c, 4, 64);  c += __shfl_xor(c, 2, 64);  c += __shfl_xor(c, 1, 64);
      if (t == 0) s0s = sp[DST_HI] + c;
    }
  }
  __syncthreads();
  int wv = (blockIdx.x * 256 + threadIdx.x) >> 6;
  int lane = threadIdx.x & 63;
  if (wv >= NN) return;
  int b0 = sp[wv], b1 = sp[wv + 1];
  int n = b1 - b0;
  int s0 = s0s;
  if (n > 64) {  // 64<n<=96 safety path (never hit at Poisson(16))
    if (lane == 0) {
      int es[PAD], ss[PAD];
      int nn = n > PAD ? PAD : n;
      for (int i = 0; i < nn; ++i) { int4 pe = pad4[wv * PAD + i]; es[i] = pe.x; ss[i] = pe.y; }
      for (int i = 1; i < nn; ++i) {
        int ve = es[i], vs = ss[i]; int j = i - 1;
        while (j >= 0 && es[j] > ve) { es[j + 1] = es[j]; ss[j + 1] = ss[j]; --j; }
        es[j + 1] = ve; ss[j + 1] = vs;
      }
      for (int i = 0; i < nn; ++i) {
        int vs = ss[i];
        cnf[b0 + i] = make_int2(vs, __float_as_int(1.0f / dout[vs]));
        int j = b0 + i - s0; if (j < 0) j += NE;
        cnr[es[i]] = make_int2(wv, __float_as_int(1.0f / din[rawsrc[j]]));
      }
    }
    return;
  }
  unsigned long long k = ~0ULL;
  if (lane < n) {
    int4 pe = pad4[wv * PAD + lane];   // coalesced row read
    k = ((unsigned long long)(unsigned)pe.x << 32) | (unsigned)pe.y;  // key=e, payload=src
  }
  if (n > 1) {
#pragma unroll
    for (int kk = 2; kk <= 64; kk <<= 1) {
#pragma unroll
      for (int j = kk >> 1; j > 0; j >>= 1) {
        unsigned long long o = __shfl_xor(k, j, 64);
        bool lower = (lane & j) == 0;
        bool asc = (lane & kk) == 0;
        bool keepmin = (lower == asc);
        if (keepmin ? (o < k) : (o > k)) k = o;
      }
    }
  }
  if (lane < n) {
    int ve = (int)(k >> 32);
    int vs = (int)(k & 0xffffffffu);
    cnf[b0 + lane] = make_int2(vs, __float_as_int(1.0f / dout[vs]));   // coalesced
    int j = b0 + lane - s0; if (j < 0) j += NE;
    cnr[ve] = make_int2(wv, __float_as_int(1.0f / din[rawsrc[j]]));    // the one scatter
  }
}

// ---- fused pair of gather props, FP16 gather operand (1 line/row vs 2; Xh fits XCD L2;
//      11-bit mantissa: ~8x less rounding than the failed bf16 — lesson R13):
//      accumulate fp32, out fp32 (+ optional fp16 copy for the next prop level). ----
__global__ __launch_bounds__(256) void k_prop2(const unsigned short* __restrict__ inA, const int* __restrict__ rpA,
                                               const int2* __restrict__ cnA, float* __restrict__ outA,
                                               unsigned short* __restrict__ outAh,
                                               const unsigned short* __restrict__ inB, const int* __restrict__ rpB,
                                               const int2* __restrict__ cnB, float* __restrict__ outB,
                                               unsigned short* __restrict__ outBh,
                                               const float* __restrict__ sub, float mul) {
  int t = blockIdx.x * 256 + threadIdx.x;
  const int half = NN * 8;
  const unsigned short* in; const int* rp; const int2* cn; float* out; unsigned short* outh;
  if (t < half) { in = inA; rp = rpA; cn = cnA; out = outA; outh = outAh; }
  else          { in = inB; rp = rpB; cn = cnB; out = outB; outh = outBh; t -= half; }
  int r = t >> 3;
  if (r >= NN) return;
  int lane8 = t & 7;
  int c4 = lane8 * 4;
  int b = rp[r], e2 = rp[r + 1];
  float a0[4] = {0.f, 0.f, 0.f, 0.f}, a1[4] = {0.f, 0.f, 0.f, 0.f};
  int p = b;
#define GATH(cc, ww) { \
    uint2 bv = *(const uint2*)&in[(cc) * 32 + c4]; \
    float2 f01 = __half22float2(*(const __half2*)&bv.x); \
    float2 f23 = __half22float2(*(const __half2*)&bv.y); \
    float* a = (jj & 1) ? a1 : a0; \
    a[0] += (ww) * f01.x; a[1] += (ww) * f01.y; \
    a[2] += (ww) * f23.x; a[3] += (ww) * f23.y; }
  for (; p + 16 <= e2; p += 16) {
    int2 u = cn[p + lane8];              // both chunk-loads in flight before any gather
    int2 v = cn[p + 8 + lane8];
#pragma unroll
    for (int jj = 0; jj < 8; ++jj) {
      int col = __shfl(u.x, jj, 8);
      float w = __int_as_float(__shfl(u.y, jj, 8));
      GATH(col, w)
    }
#pragma unroll
    for (int jj = 0; jj < 8; ++jj) {
      int col = __shfl(v.x, jj, 8);
      float w = __int_as_float(__shfl(v.y, jj, 8));
      GATH(col, w)
    }
  }
  for (; p + 8 <= e2; p += 8) {
    int2 u = cn[p + lane8];
#pragma unroll
    for (int jj = 0; jj < 8; ++jj) {
      int col = __shfl(u.x, jj, 8);
      float w = __int_as_float(__shfl(u.y, jj, 8));
      GATH(col, w)
    }
  }
  for (int jj = 0; p < e2; ++p) {
    int2 c1 = cn[p];
    float w = __int_as_float(c1.y);
    GATH(c1.x, w)
  }
#undef GATH
  float ax = a0[0] + a1[0], ay = a0[1] + a1[1], az = a0[2] + a1[2], aw = a0[3] + a1[3];
  float4 o;
  if (sub) {
    const float4 s = *(const float4*)&sub[r * 32 + c4];
    o.x = mul * ax - s.x; o.y = mul * ay - s.y; o.z = mul * az - s.z; o.w = mul * aw - s.w;
  } else {
    o.x = ax; o.y = ay; o.z = az; o.w = aw;
  }
  *(float4*)&out[r * 32 + c4] = o;
  if (outh) {
    ushort4 oh = make_ushort4(f2h(o.x), f2h(o.y), f2h(o.z), f2h(o.w));
    *(ushort4*)&outh[r * 32 + c4] = oh;
  }
}

// ---- register-blocked GEMM + GRU epilogue: 64x128 tile, K-chunk 32 (25.6 KB LDS) ----
__global__ __launch_bounds__(256) void k_gemm(const float* __restrict__ X, const float* __restrict__ T1o,
                                              const float* __restrict__ T1i, const float* __restrict__ T2o,
                                              const float* __restrict__ T2i,
                                              const float* __restrict__ Weff,
                                              const float* __restrict__ bz, const float* __restrict__ bh,
                                              float* __restrict__ out) {
  __shared__ float Ws[32][128];
  __shared__ float Fs[64][36];
  const int tid = threadIdx.x;
  const int tx = tid & 15, ty = tid >> 4;
  const int rb = blockIdx.x * 64;
  float accz[4][4] = {{0.f}}, acch[4][4] = {{0.f}};

  for (int kc = 0; kc < 160; kc += 32) {
    __syncthreads();
#pragma unroll
    for (int i = 0; i < 4; ++i) {
      int q = tid + i * 256;
      int row = q >> 5, cv = q & 31;
      *(float4*)&Ws[row][cv * 4] = *(const float4*)&Weff[(kc + row) * 128 + cv * 4];
    }
    const int blk = kc >> 5;
    const float* base = (blk == 0) ? X : (blk == 1) ? T1o : (blk == 2) ? T1i : (blk == 3) ? T2o : T2i;
#pragma unroll
    for (int i = 0; i < 2; ++i) {
      int q = tid + i * 256;
      int row = q >> 3, kv = q & 7;
      int gr = rb + row;
      float4 v = make_float4(0.f, 0.f, 0.f, 0.f);
      if (gr < NN) v = *(const float4*)&base[gr * 32 + kv * 4];
      *(float4*)&Fs[row][kv * 4] = v;
    }
    __syncthreads();
#pragma unroll
    for (int k = 0; k < 32; ++k) {
      float fa[4];
#pragma unroll
      for (int ri = 0; ri < 4; ++ri) fa[ri] = Fs[ty * 4 + ri][k];
      float4 wz = *(float4*)&Ws[k][tx * 4];
      float4 wh = *(float4*)&Ws[k][64 + tx * 4];
#pragma unroll
      for (int ri = 0; ri < 4; ++ri) {
        accz[ri][0] += fa[ri] * wz.x; accz[ri][1] += fa[ri] * wz.y;
        accz[ri][2] += fa[ri] * wz.z; accz[ri][3] += fa[ri] * wz.w;
        acch[ri][0] += fa[ri] * wh.x; acch[ri][1] += fa[ri] * wh.y;
        acch[ri][2] += fa[ri] * wh.z; acch[ri][3] += fa[ri] * wh.w;
      }
    }
  }

  const float4 bzv = *(const float4*)&bz[tx * 4];
  const float4 bhv = *(const float4*)&bh[tx * 4];
#pragma unroll
  for (int ri = 0; ri < 4; ++ri) {
    int r = rb + ty * 4 + ri;
    if (r < NN) {
      float4 o;
      float z, h;
      z = 1.f / (1.f + expf(-(accz[ri][0] + bzv.x))); h = tanhf(acch[ri][0] + bhv.x); o.x = (1.f - z) * h;
      z = 1.f / (1.f + expf(-(accz[ri][1] + bzv.y))); h = tanhf(acch[ri][1] + bhv.y); o.y = (1.f - z) * h;
      z = 1.f / (1.f + expf(-(accz[ri][2] + bzv.z))); h = tanhf(acch[ri][2] + bhv.z); o.z = (1.f - z) * h;
      z = 1.f / (1.f + expf(-(accz[ri][3] + bzv.w))); h = tanhf(acch[ri][3] + bhv.w); o.w = (1.f - z) * h;
      *(float4*)&out[r * 64 + tx * 4] = o;
    }
  }
}

// ---------------- launch ----------------
extern "C" void kernel_launch(void* const* d_in, const int* in_sizes, int n_in,
                              void* d_out, int out_size, void* d_ws, size_t ws_size,
                              hipStream_t stream) {
  const float* X  = (const float*)d_in[0];
  const int*   ei = (const int*)d_in[1];
  const float* ew = (const float*)d_in[2];
  const float* Wz = (const float*)d_in[3];
  const float* bz = (const float*)d_in[4];
  const float* Wh = (const float*)d_in[7];
  const float* bh = (const float*)d_in[8];
  float* out = (float*)d_out;
  const int* src = ei;
  const int* dst = ei + NE;

  char* p = (char*)d_ws;
  auto alloc = [&](size_t bytes) -> char* {
    char* r = p;
    p += (bytes + 255) & ~(size_t)255;
    return r;
  };
  float* T1o  = (float*)alloc((size_t)NN * 32 * 4);
  float* T1i  = (float*)alloc((size_t)NN * 32 * 4);
  float* T2o  = (float*)alloc((size_t)NN * 32 * 4);
  float* T2i  = (float*)alloc((size_t)NN * 32 * 4);
  unsigned short* Xh   = (unsigned short*)alloc((size_t)NN * 32 * 2);
  unsigned short* T1oh = (unsigned short*)alloc((size_t)NN * 32 * 2);
  unsigned short* T1ih = (unsigned short*)alloc((size_t)NN * 32 * 2);
  int4*  pad4    = (int4*)alloc((size_t)NN * PAD * 16);   // 76.8 MB packed, no memset needed
  int2*  cnf     = (int2*)alloc((size_t)NE * 8);
  int2*  cnr     = (int2*)alloc((size_t)NE * 8);
  int*   sp      = (int*)alloc((NN + 1) * 4);
  int*   rptr    = (int*)alloc((NN + 1) * 4);
  int*   cnt     = (int*)alloc(NN * 4);
  int*   partial = (int*)alloc(64 * 4);
  float* dout    = (float*)alloc(NN * 4);
  float* din     = (float*)alloc(NN * 4);
  float* Weff    = (float*)alloc(160 * 128 * 4);

  hipMemsetAsync(cnt, 0, NN * 4, stream);

  k_A<<<3792, 256, 0, stream>>>(X, src, dst, ew, cnt, pad4, rptr, dout, Wz, Wh, Weff, Xh);
  k_B<<<440, 1024, 0, stream>>>(cnt, sp, partial, pad4, din);        // scan1 ∥ din
  k_C<<<196, 256, 0, stream>>>(sp, partial);                         // scan3
  k_sortw<<<12500, 256, 0, stream>>>(sp, pad4, src, cnt, dout, din, cnf, cnr);  // s0+sort+cnf+cnr

  // T1 = P(Xh) both directions, fp32 out + fp16 copies for the next level
  k_prop2<<<3125, 256, 0, stream>>>(Xh, sp, cnf, T1o, T1oh,
                                    Xh, rptr, cnr, T1i, T1ih, nullptr, 1.f);
  // T2 = 2*P(T1h) - X (fused Chebyshev), fp32 out only
  k_prop2<<<3125, 256, 0, stream>>>(T1oh, sp, cnf, T2o, nullptr,
                                    T1ih, rptr, cnr, T2i, nullptr, X, 2.f);

  k_gemm<<<782, 256, 0, stream>>>(X, T1o, T1i, T2o, T2i, Weff, bz, bh, out);
}